// Round 1
// baseline (20592.644 us; speedup 1.0000x reference)
//
#include <hip/hip_runtime.h>
#include <math.h>

#define Bv 256
#define Pv 361
#define Fv 20
#define NROW (Bv*Pv)   // 92416 = 361 * 256

__device__ __forceinline__ float gelu_f(float z){
    return 0.5f*z*(1.0f + erff(z*0.70710678118654752440f));
}

__device__ __forceinline__ void cpb(float* dst, const float* __restrict__ src, int n){
    for (int i = threadIdx.x; i < n; i += 256) dst[i] = src[i];
}

// ---------------- Kernel 1: per-frequency branch+fusion, partial mean over f ----------------
__global__ __launch_bounds__(256, 2) void k_branch(
    const float* __restrict__ x,
    const float* __restrict__ rw1, const float* __restrict__ rb1,
    const float* __restrict__ rw2, const float* __restrict__ rb2,
    const float* __restrict__ rw3, const float* __restrict__ rb3,
    const float* __restrict__ iw1, const float* __restrict__ ib1,
    const float* __restrict__ iw2, const float* __restrict__ ib2,
    const float* __restrict__ iw3, const float* __restrict__ ib3,
    const float* __restrict__ fw1, const float* __restrict__ fb1,
    const float* __restrict__ fw2, const float* __restrict__ fb2,
    float* __restrict__ partial, int nf)
{
    __shared__ __align__(16) float sm[6400];
    enum { RW1=0, RB1=16, RW2=32, RB2=544, RW3=576, RB3=1600,
           IW1=1632, IB1=1648, IW2=1664, IB2=2176, IW3=2208, IB3=3232,
           FW1=3264, FB1=5312, FW2=5344, FB2=6368 };

    const int row = blockIdx.x * 256 + threadIdx.x;     // 361*256 == 92416 exactly
    const int g   = blockIdx.y;
    const float2* __restrict__ x2 = (const float2*)x;

    float acc[32];
    #pragma unroll
    for (int k = 0; k < 32; ++k) acc[k] = 0.f;

    for (int ff = 0; ff < nf; ++ff){
        const int f = g*nf + ff;
        __syncthreads();   // protect previous iteration's reads
        cpb(sm+RW1, rw1+f*16,   16);   cpb(sm+RB1, rb1+f*16,   16);
        cpb(sm+RW2, rw2+f*512,  512);  cpb(sm+RB2, rb2+f*32,   32);
        cpb(sm+RW3, rw3+f*1024, 1024); cpb(sm+RB3, rb3+f*32,   32);
        cpb(sm+IW1, iw1+f*16,   16);   cpb(sm+IB1, ib1+f*16,   16);
        cpb(sm+IW2, iw2+f*512,  512);  cpb(sm+IB2, ib2+f*32,   32);
        cpb(sm+IW3, iw3+f*1024, 1024); cpb(sm+IB3, ib3+f*32,   32);
        cpb(sm+FW1, fw1+f*2048, 2048); cpb(sm+FB1, fb1+f*32,   32);
        cpb(sm+FW2, fw2+f*1024, 1024); cpb(sm+FB2, fb2+f*32,   32);
        __syncthreads();

        const float2 xv = x2[(size_t)row*Fv + f];

        float ro[32], io[32];
        // ---- real branch ----
        {
            float h1[16];
            #pragma unroll
            for (int i = 0; i < 16; ++i) h1[i] = gelu_f(xv.x*sm[RW1+i] + sm[RB1+i]);
            float h2[32];
            #pragma unroll
            for (int k = 0; k < 32; ++k) h2[k] = sm[RB2+k];
            for (int i = 0; i < 16; ++i){
                const float hi = h1[i];
                const float4* w = (const float4*)&sm[RW2 + i*32];
                #pragma unroll
                for (int k4 = 0; k4 < 8; ++k4){
                    float4 ww = w[k4];
                    h2[4*k4+0] += hi*ww.x; h2[4*k4+1] += hi*ww.y;
                    h2[4*k4+2] += hi*ww.z; h2[4*k4+3] += hi*ww.w;
                }
            }
            #pragma unroll
            for (int k = 0; k < 32; ++k) h2[k] = gelu_f(h2[k]);
            #pragma unroll
            for (int k = 0; k < 32; ++k) ro[k] = sm[RB3+k];
            for (int i = 0; i < 32; ++i){
                const float hi = h2[i];
                const float4* w = (const float4*)&sm[RW3 + i*32];
                #pragma unroll
                for (int k4 = 0; k4 < 8; ++k4){
                    float4 ww = w[k4];
                    ro[4*k4+0] += hi*ww.x; ro[4*k4+1] += hi*ww.y;
                    ro[4*k4+2] += hi*ww.z; ro[4*k4+3] += hi*ww.w;
                }
            }
        }
        // ---- imag branch ----
        {
            float h1[16];
            #pragma unroll
            for (int i = 0; i < 16; ++i) h1[i] = gelu_f(xv.y*sm[IW1+i] + sm[IB1+i]);
            float h2[32];
            #pragma unroll
            for (int k = 0; k < 32; ++k) h2[k] = sm[IB2+k];
            for (int i = 0; i < 16; ++i){
                const float hi = h1[i];
                const float4* w = (const float4*)&sm[IW2 + i*32];
                #pragma unroll
                for (int k4 = 0; k4 < 8; ++k4){
                    float4 ww = w[k4];
                    h2[4*k4+0] += hi*ww.x; h2[4*k4+1] += hi*ww.y;
                    h2[4*k4+2] += hi*ww.z; h2[4*k4+3] += hi*ww.w;
                }
            }
            #pragma unroll
            for (int k = 0; k < 32; ++k) h2[k] = gelu_f(h2[k]);
            #pragma unroll
            for (int k = 0; k < 32; ++k) io[k] = sm[IB3+k];
            for (int i = 0; i < 32; ++i){
                const float hi = h2[i];
                const float4* w = (const float4*)&sm[IW3 + i*32];
                #pragma unroll
                for (int k4 = 0; k4 < 8; ++k4){
                    float4 ww = w[k4];
                    io[4*k4+0] += hi*ww.x; io[4*k4+1] += hi*ww.y;
                    io[4*k4+2] += hi*ww.z; io[4*k4+3] += hi*ww.w;
                }
            }
        }
        // ---- fusion: cat(ro,io) @ fw1 + fb1 -> gelu -> @ fw2 + fb2, accumulate ----
        {
            float hf[32];
            #pragma unroll
            for (int k = 0; k < 32; ++k) hf[k] = sm[FB1+k];
            for (int i = 0; i < 32; ++i){
                const float a = ro[i];
                const float4* w = (const float4*)&sm[FW1 + i*32];
                #pragma unroll
                for (int k4 = 0; k4 < 8; ++k4){
                    float4 ww = w[k4];
                    hf[4*k4+0] += a*ww.x; hf[4*k4+1] += a*ww.y;
                    hf[4*k4+2] += a*ww.z; hf[4*k4+3] += a*ww.w;
                }
            }
            for (int i = 0; i < 32; ++i){
                const float a = io[i];
                const float4* w = (const float4*)&sm[FW1 + (32+i)*32];
                #pragma unroll
                for (int k4 = 0; k4 < 8; ++k4){
                    float4 ww = w[k4];
                    hf[4*k4+0] += a*ww.x; hf[4*k4+1] += a*ww.y;
                    hf[4*k4+2] += a*ww.z; hf[4*k4+3] += a*ww.w;
                }
            }
            #pragma unroll
            for (int k = 0; k < 32; ++k) hf[k] = gelu_f(hf[k]);
            #pragma unroll
            for (int k = 0; k < 32; ++k) acc[k] += sm[FB2+k];
            for (int i = 0; i < 32; ++i){
                const float a = hf[i];
                const float4* w = (const float4*)&sm[FW2 + i*32];
                #pragma unroll
                for (int k4 = 0; k4 < 8; ++k4){
                    float4 ww = w[k4];
                    acc[4*k4+0] += a*ww.x; acc[4*k4+1] += a*ww.y;
                    acc[4*k4+2] += a*ww.z; acc[4*k4+3] += a*ww.w;
                }
            }
        }
    }

    float4* o = (float4*)(partial + ((size_t)g*NROW + row)*32);
    #pragma unroll
    for (int k4 = 0; k4 < 8; ++k4)
        o[k4] = make_float4(acc[4*k4+0], acc[4*k4+1], acc[4*k4+2], acc[4*k4+3]);
}

// ---------------- Kernel 2: reduce partials + freq branch + final fusion ----------------
__global__ __launch_bounds__(256, 2) void k_tail(
    const float* __restrict__ x,
    const float* __restrict__ freq_imp,
    const float* __restrict__ pw1, const float* __restrict__ pb1,
    const float* __restrict__ pw2, const float* __restrict__ pb2,
    const float* __restrict__ pw3, const float* __restrict__ pb3,
    const float* __restrict__ gw1, const float* __restrict__ gb1,
    const float* __restrict__ gw2, const float* __restrict__ gb2,
    const float* __restrict__ partial, int ng,
    float* __restrict__ out)
{
    __shared__ __align__(16) float sm[16576];
    const int row = blockIdx.x * 256 + threadIdx.x;

    // sum partial cf over groups
    float acc[32];
    #pragma unroll
    for (int k = 0; k < 32; ++k) acc[k] = 0.f;
    for (int g = 0; g < ng; ++g){
        const float4* pg = (const float4*)(partial + ((size_t)g*NROW + row)*32);
        #pragma unroll
        for (int k4 = 0; k4 < 8; ++k4){
            float4 v = pg[k4];
            acc[4*k4+0] += v.x; acc[4*k4+1] += v.y;
            acc[4*k4+2] += v.z; acc[4*k4+3] += v.w;
        }
    }

    // softmax(freq_imp) and magnitude-weighted inputs
    float w[20];
    float mx = -1e30f;
    #pragma unroll
    for (int f = 0; f < 20; ++f){ w[f] = freq_imp[f]; mx = fmaxf(mx, w[f]); }
    float s = 0.f;
    #pragma unroll
    for (int f = 0; f < 20; ++f){ w[f] = expf(w[f]-mx); s += w[f]; }
    const float inv = 1.f/s;
    float mw[20];
    const float2* __restrict__ xr = (const float2*)x + (size_t)row*Fv;
    #pragma unroll
    for (int f = 0; f < 20; ++f){
        float2 v = xr[f];
        mw[f] = sqrtf(v.x*v.x + v.y*v.y + 1e-8f) * (w[f]*inv);
    }

    // phase 1: freq MLP weights
    enum { PW1=0, PB1=1280, PW2=1344, PB2=5440, PW3=5504, PB3=7552 };
    cpb(sm+PW1, pw1, 1280); cpb(sm+PB1, pb1, 64);
    cpb(sm+PW2, pw2, 4096); cpb(sm+PB2, pb2, 64);
    cpb(sm+PW3, pw3, 2048); cpb(sm+PB3, pb3, 32);
    __syncthreads();

    float t1[64];
    #pragma unroll
    for (int j = 0; j < 64; ++j) t1[j] = sm[PB1+j];
    for (int f = 0; f < 20; ++f){
        const float a = mw[f];
        const float4* wv = (const float4*)&sm[PW1 + f*64];
        #pragma unroll
        for (int j4 = 0; j4 < 16; ++j4){
            float4 ww = wv[j4];
            t1[4*j4+0] += a*ww.x; t1[4*j4+1] += a*ww.y;
            t1[4*j4+2] += a*ww.z; t1[4*j4+3] += a*ww.w;
        }
    }
    #pragma unroll
    for (int j = 0; j < 64; ++j) t1[j] = gelu_f(t1[j]);

    float t2[64];
    #pragma unroll
    for (int j = 0; j < 64; ++j) t2[j] = sm[PB2+j];
    for (int i = 0; i < 64; ++i){
        const float a = t1[i];
        const float4* wv = (const float4*)&sm[PW2 + i*64];
        #pragma unroll
        for (int j4 = 0; j4 < 16; ++j4){
            float4 ww = wv[j4];
            t2[4*j4+0] += a*ww.x; t2[4*j4+1] += a*ww.y;
            t2[4*j4+2] += a*ww.z; t2[4*j4+3] += a*ww.w;
        }
    }
    #pragma unroll
    for (int j = 0; j < 64; ++j) t2[j] = gelu_f(t2[j]);

    float ffr[32];
    #pragma unroll
    for (int k = 0; k < 32; ++k) ffr[k] = sm[PB3+k];
    for (int i = 0; i < 64; ++i){
        const float a = t2[i];
        const float4* wv = (const float4*)&sm[PW3 + i*32];
        #pragma unroll
        for (int k4 = 0; k4 < 8; ++k4){
            float4 ww = wv[k4];
            ffr[4*k4+0] += a*ww.x; ffr[4*k4+1] += a*ww.y;
            ffr[4*k4+2] += a*ww.z; ffr[4*k4+3] += a*ww.w;
        }
    }
    __syncthreads();

    // phase 2: final fusion weights (gw1 transposed for contiguous dot reads)
    enum { GW1T=0, GB1=8192, GW2=8320, GB2=16512 };
    for (int idx = threadIdx.x; idx < 8192; idx += 256){
        int j = idx >> 6, i = idx & 63;
        sm[GW1T + idx] = gw1[i*128 + j];
    }
    cpb(sm+GB1, gb1, 128); cpb(sm+GW2, gw2, 8192); cpb(sm+GB2, gb2, 64);
    __syncthreads();

    float u[64];
    #pragma unroll
    for (int k = 0; k < 32; ++k){ u[k] = ffr[k]; u[32+k] = acc[k]*(1.f/20.f); }

    float o[64];
    #pragma unroll
    for (int k = 0; k < 64; ++k) o[k] = sm[GB2+k];

    for (int j = 0; j < 128; ++j){
        // dot(u, gw1[:,j]) with 4-way split accumulators (avoid 64-long dep chain)
        float d0 = 0.f, d1 = 0.f, d2 = 0.f, d3 = 0.f;
        const float4* wv = (const float4*)&sm[GW1T + j*64];
        #pragma unroll
        for (int i4 = 0; i4 < 16; ++i4){
            float4 ww = wv[i4];
            d0 += u[4*i4+0]*ww.x; d1 += u[4*i4+1]*ww.y;
            d2 += u[4*i4+2]*ww.z; d3 += u[4*i4+3]*ww.w;
        }
        const float d = gelu_f(sm[GB1+j] + ((d0+d1)+(d2+d3)));
        const float4* w2 = (const float4*)&sm[GW2 + j*64];
        #pragma unroll
        for (int k4 = 0; k4 < 16; ++k4){
            float4 ww = w2[k4];
            o[4*k4+0] += d*ww.x; o[4*k4+1] += d*ww.y;
            o[4*k4+2] += d*ww.z; o[4*k4+3] += d*ww.w;
        }
    }

    float4* op = (float4*)(out + (size_t)row*64);
    #pragma unroll
    for (int k4 = 0; k4 < 16; ++k4)
        op[k4] = make_float4(o[4*k4+0], o[4*k4+1], o[4*k4+2], o[4*k4+3]);
}

extern "C" void kernel_launch(void* const* d_in, const int* in_sizes, int n_in,
                              void* d_out, int out_size, void* d_ws, size_t ws_size,
                              hipStream_t stream) {
    (void)in_sizes; (void)n_in; (void)out_size;
    const float* x   = (const float*)d_in[0];
    const float* rw1 = (const float*)d_in[1];  const float* rb1 = (const float*)d_in[2];
    const float* rw2 = (const float*)d_in[3];  const float* rb2 = (const float*)d_in[4];
    const float* rw3 = (const float*)d_in[5];  const float* rb3 = (const float*)d_in[6];
    const float* iw1 = (const float*)d_in[7];  const float* ib1 = (const float*)d_in[8];
    const float* iw2 = (const float*)d_in[9];  const float* ib2 = (const float*)d_in[10];
    const float* iw3 = (const float*)d_in[11]; const float* ib3 = (const float*)d_in[12];
    const float* fw1 = (const float*)d_in[13]; const float* fb1 = (const float*)d_in[14];
    const float* fw2 = (const float*)d_in[15]; const float* fb2 = (const float*)d_in[16];
    const float* fim = (const float*)d_in[17];
    const float* pw1 = (const float*)d_in[18]; const float* pb1 = (const float*)d_in[19];
    const float* pw2 = (const float*)d_in[20]; const float* pb2 = (const float*)d_in[21];
    const float* pw3 = (const float*)d_in[22]; const float* pb3 = (const float*)d_in[23];
    const float* gw1 = (const float*)d_in[24]; const float* gb1 = (const float*)d_in[25];
    const float* gw2 = (const float*)d_in[26]; const float* gb2 = (const float*)d_in[27];
    float* out = (float*)d_out;
    float* partial = (float*)d_ws;

    const size_t per = (size_t)NROW * 32 * sizeof(float);   // 11.83 MB per f-group
    int ng;
    if      (ws_size >= 5*per) ng = 5;
    else if (ws_size >= 4*per) ng = 4;
    else if (ws_size >= 2*per) ng = 2;
    else                       ng = 1;
    const int nf = Fv / ng;

    dim3 g1(361, ng);
    hipLaunchKernelGGL(k_branch, g1, dim3(256), 0, stream,
                       x, rw1, rb1, rw2, rb2, rw3, rb3,
                       iw1, ib1, iw2, ib2, iw3, ib3,
                       fw1, fb1, fw2, fb2, partial, nf);
    hipLaunchKernelGGL(k_tail, dim3(361), dim3(256), 0, stream,
                       x, fim, pw1, pb1, pw2, pb2, pw3, pb3,
                       gw1, gb1, gw2, gb2, partial, ng, out);
}